// Round 14
// baseline (286.861 us; speedup 1.0000x reference)
//
#include <hip/hip_runtime.h>

#define V_ 25000
#define F_ 8192
#define E_ (3 * F_) // 24576

constexpr int CAP  = 101;      // per-edge cap; face clip at 100 makes this lossless
constexpr int GD   = 8;        // grid cells per axis (unit cells over [-4,4), clamped)
constexpr int NC   = GD*GD*GD; // 512 cells
constexpr int CAPC = 6144;     // per-cell list capacity (center cell ~4400 expected)
constexpr int FLATCAP = 384;   // max flat chunks on the pipelined path

constexpr int CNT_BLOCKS = E_ / 4;  // 6144 blocks, ONE edge per wave (R13 lesson)
constexpr int GROUPS     = 64;      // arrival-tree fanout; 96 arrivals/counter,
constexpr int PER_GROUP  = CNT_BLOCKS / GROUPS; // staggered -> cheap (R9 lesson)

// ws layout:
//   C4        float4[E_]        @ 0           (cx,cy,cz, __int_as_float(cell))
//   cellList  float4[NC*CAPC]   @ 393,216     (50,331,648 B)
//   cellCount int[NC]           @ 50,724,864  \
//   ndone1    int[64*32]        @ 50,726,912   | one 10,368 B memset
//   ndone2    int               @ 50,735,104  /
//   cnt       int[E_]           @ 50,735,232  (fully overwritten before read)
constexpr size_t OFF_LIST = 393216;
constexpr size_t OFF_CCNT = 50724864;
constexpr size_t OFF_ND1  = OFF_CCNT + 2048;
constexpr size_t OFF_ND2  = OFF_ND1 + 8192;
constexpr size_t OFF_CNT  = OFF_ND2 + 128;
constexpr size_t ZERO_BYTES = 2048 + 8192 + 128;

// 26 neighbor patterns in DESCENDING center-ward score; applied as
// offset = pattern * (dirx,diry,dirz). Bijective onto {-1,0,1}^3 \ {0}.
__device__ const int PPAT[26][3] = {
    { 1, 1, 1},
    { 1, 1, 0},{ 1, 0, 1},{ 0, 1, 1},
    { 1, 0, 0},{ 0, 1, 0},{ 0, 0, 1},{ 1, 1,-1},{ 1,-1, 1},{-1, 1, 1},
    { 1,-1, 0},{ 1, 0,-1},{ 0, 1,-1},{-1, 1, 0},{-1, 0, 1},{ 0,-1, 1},
    {-1, 0, 0},{ 0,-1, 0},{ 0, 0,-1},{-1,-1, 1},{-1, 1,-1},{ 1,-1,-1},
    {-1,-1, 0},{-1, 0,-1},{ 0,-1,-1},
    {-1,-1,-1}
};

__device__ __forceinline__ int cell_coord(float c)
{
    return min(GD-1, max(0, (int)floorf(c) + GD/2));
}

// 96 blocks x 256: centroid + cell, LDS-rank counting-append into per-cell lists.
__global__ __launch_bounds__(256) void build_kernel(
    const float* __restrict__ vertices, const int* __restrict__ faces,
    float4* __restrict__ C4, float4* __restrict__ cellList,
    int* __restrict__ cellCount)
{
    __shared__ int lh[NC];
    __shared__ int lbase[NC];
    for (int i = threadIdx.x; i < NC; i += 256) lh[i] = 0;
    __syncthreads();

    const int e = blockIdx.x * 256 + threadIdx.x;
    int f, i0, i1;
    if (e < F_)        { f = e;        i0 = 0; i1 = 1; }
    else if (e < 2*F_) { f = e - F_;   i0 = 1; i1 = 2; }
    else               { f = e - 2*F_; i0 = 2; i1 = 0; }
    int a = faces[f*3 + i0];
    int b = faces[f*3 + i1];
    float cx = 0.5f*(vertices[a*3+0] + vertices[b*3+0]);
    float cy = 0.5f*(vertices[a*3+1] + vertices[b*3+1]);
    float cz = 0.5f*(vertices[a*3+2] + vertices[b*3+2]);
    int cell = (cell_coord(cz)*GD + cell_coord(cy))*GD + cell_coord(cx);
    int rank = atomicAdd(&lh[cell], 1);
    __syncthreads();
    for (int i = threadIdx.x; i < NC; i += 256) {
        int c = lh[i];
        if (c) lbase[i] = atomicAdd(&cellCount[i], c);
    }
    __syncthreads();
    C4[e] = make_float4(cx, cy, cz, __int_as_float(cell));
    cellList[(size_t)cell * CAPC + lbase[cell] + rank] = make_float4(cx, cy, cz, 0.f);
}

// R12's per-edge counter, verbatim. `flat` is this wave's LDS row.
__device__ __forceinline__ int count_edge(
    int e, const float4* __restrict__ C4, const float4* __restrict__ cellList,
    const int* __restrict__ cellCount, unsigned* flat, int lane)
{
    float4 s = C4[e];                          // wave-uniform broadcast
    const float ex = s.x, ey = s.y, ez = s.z;
    const int   cell = __float_as_int(s.w);
    const int ix = cell & 7, iy = (cell >> 3) & 7, iz = cell >> 6;
    const float d2t = (1.0f + 1e-6f) * (1.0f + 1e-6f);

    int count = 0;

    // ---- own cell (1-deep prefetch; ~90% of edges cap-exit here) ----
    {
        const int n = cellCount[cell];         // >=1 (own edge)
        const float4* __restrict__ L = cellList + (size_t)cell * CAPC;
        float4 cur = L[lane];
        for (int base = 0;;) {
            int nb = base + 64;
            bool more = nb < n;
            float4 nxt;
            if (more) nxt = L[nb + lane];
            float dx = ex - cur.x, dy = ey - cur.y, dz = ez - cur.z;
            float d2 = dx*dx + dy*dy + dz*dz;
            bool c = (base + lane < n) && (d2 < d2t);
            count += __popcll(__ballot(c));
            if (count >= CAP) goto done;       // wave-uniform
            if (!more) break;
            cur = nxt; base = nb;
        }
    }

    // ---- survivors: flat chunk list over 26 cells, densest-first ----
    {
        const int dirx = (ix <= 3) ? 1 : -1;
        const int diry = (iy <= 3) ? 1 : -1;
        const int dirz = (iz <= 3) ? 1 : -1;

        int cq = 0, nq = 0, cellq = cell;
        if (lane < 26) {
            int ox = PPAT[lane][0] * dirx;
            int oy = PPAT[lane][1] * diry;
            int oz = PPAT[lane][2] * dirz;
            int x = ix + ox, y = iy + oy, z = iz + oz;
            if (((unsigned)x < (unsigned)GD) & ((unsigned)y < (unsigned)GD) &
                ((unsigned)z < (unsigned)GD)) {
                cellq = cell + oz*64 + oy*8 + ox;
                nq = cellCount[cellq];
                cq = (nq + 63) >> 6;
            }
        }
        int incl = cq;
#pragma unroll
        for (int d = 1; d < 64; d <<= 1) {
            int t = __shfl_up(incl, d, 64);
            if (lane >= d) incl += t;
        }
        const int T = __shfl(incl, 63);        // total chunks (lanes>=26 add 0)
        const int excl = incl - cq;

        if (T == 0) goto done;

        if (T > FLATCAP) {
            // rare exact fallback: simple serial scan, same cells, same order
            for (int q = 0; q < 26; ++q) {
                int ox = PPAT[q][0] * dirx, oy = PPAT[q][1] * diry,
                    oz = PPAT[q][2] * dirz;
                int x = ix + ox, y = iy + oy, z = iz + oz;
                if (((unsigned)x >= (unsigned)GD) | ((unsigned)y >= (unsigned)GD) |
                    ((unsigned)z >= (unsigned)GD)) continue;
                int nc2 = cell + oz*64 + oy*8 + ox;
                int n = cellCount[nc2];
                const float4* __restrict__ L = cellList + (size_t)nc2 * CAPC;
                for (int base = 0; base < n; base += 64) {
                    float4 t4 = L[base + lane];
                    float dx = ex - t4.x, dy = ey - t4.y, dz = ez - t4.z;
                    float d2 = dx*dx + dy*dy + dz*dz;
                    bool c = (base + lane < n) && (d2 < d2t);
                    count += __popcll(__ballot(c));
                    if (count >= CAP) goto done;
                }
            }
            goto done;
        }

        // emit entries: cell(9b)<<14 | chunk(7b)<<7 | nvalid(7b)
        for (int k = 0; k < cq; ++k)
            flat[excl + k] =
                ((unsigned)cellq << 14) | ((unsigned)k << 7)
                | (unsigned)min(64, nq - k*64);
        {
            int pi = T + lane;                 // pads: nvalid=0, own-cell chunk 0
            if (pi < T + 12) flat[pi] = (unsigned)cell << 14;
        }
        asm volatile("s_waitcnt lgkmcnt(0)" ::: "memory"); // same-wave LDS RAW

        const int Tp = (T + 3) & ~3;

#define FADDR(E) (cellList + (size_t)((E) >> 14) * CAPC + (((E) >> 7) & 127) * 64 + lane)
#define PROC(B, EN)                                                        \
        {                                                                  \
            float dx = ex - (B).x, dy = ey - (B).y, dz = ez - (B).z;       \
            float d2 = dx*dx + dy*dy + dz*dz;                              \
            bool c = (lane < (int)((EN) & 127u)) && (d2 < d2t);            \
            count += __popcll(__ballot(c));                                \
            if (count >= CAP) goto done;                                   \
        }

        unsigned e0 = flat[0], e1 = flat[1], e2 = flat[2], e3 = flat[3];
        float4 b0 = *FADDR(e0), b1 = *FADDR(e1), b2 = *FADDR(e2), b3 = *FADDR(e3);
        for (int j = 0;; j += 4) {
            unsigned f0 = flat[j+4], f1 = flat[j+5], f2 = flat[j+6], f3 = flat[j+7];
            float4 n0 = *FADDR(f0), n1 = *FADDR(f1),
                   n2 = *FADDR(f2), n3 = *FADDR(f3);   // issued before compute
            PROC(b0, e0) PROC(b1, e1) PROC(b2, e2) PROC(b3, e3)
            if (j + 4 >= Tp) break;
            e0 = f0; e1 = f1; e2 = f2; e3 = f3;
            b0 = n0; b1 = n1; b2 = n2; b3 = n3;
        }
#undef FADDR
#undef PROC
    }
done:
    return count;
}

// 6144 blocks x 256: ONE edge per wave (R12 shape). After the block's 4 edges
// are stored, a two-level arrival tree elects the globally-last block, which
// runs the face reduce in place. Non-last blocks exit immediately.
__global__ __launch_bounds__(256) void count_kernel(
    const float4* __restrict__ C4, const float4* __restrict__ cellList,
    const int* __restrict__ cellCount, int* __restrict__ cnt,
    const float* __restrict__ probs, int* __restrict__ ndone1,
    int* __restrict__ ndone2, float* __restrict__ out)
{
    __shared__ unsigned flatLDS[4][FLATCAP + 16];
    __shared__ float wsum[4];
    __shared__ int lastFlag;
    const int wave = threadIdx.x >> 6;
    const int lane = threadIdx.x & 63;
    const int e = blockIdx.x * 4 + wave;

    int c = count_edge(e, C4, cellList, cellCount, flatLDS[wave], lane);
    if (lane == 0) cnt[e] = c;

    __syncthreads();
    if (threadIdx.x == 0) {
        __threadfence();                       // release: this block's cnt stores
        int g = blockIdx.x & (GROUPS - 1);
        int lf = 0;
        int o1 = __hip_atomic_fetch_add(&ndone1[g * 32], 1, __ATOMIC_ACQ_REL,
                                        __HIP_MEMORY_SCOPE_AGENT);
        if (o1 == PER_GROUP - 1) {             // last of this group of 96
            int o2 = __hip_atomic_fetch_add(ndone2, 1, __ATOMIC_ACQ_REL,
                                            __HIP_MEMORY_SCOPE_AGENT);
            lf = (o2 == GROUPS - 1);           // globally last block
        }
        lastFlag = lf;
    }
    __syncthreads();
    if (!lastFlag) return;

    // ---- face reduce, in the last block (pattern proven in R13: absmax 0.0) ----
    __threadfence();                           // acquire side
    float local = 0.0f;
    for (int f = threadIdx.x; f < F_; f += 256) {
        // face f's edges in the concatenated [(0,1),(1,2),(2,0)] layout
        int c0 = __hip_atomic_load(&cnt[f],        __ATOMIC_RELAXED, __HIP_MEMORY_SCOPE_AGENT);
        int c1 = __hip_atomic_load(&cnt[F_ + f],   __ATOMIC_RELAXED, __HIP_MEMORY_SCOPE_AGENT);
        int c2 = __hip_atomic_load(&cnt[2*F_ + f], __ATOMIC_RELAXED, __HIP_MEMORY_SCOPE_AGENT);
        float fc = (float)(c0 + c1 + c2);
        fc = fminf(fmaxf(fc, 0.0f), 100.0f);
        local += probs[f] * fc;
    }
#pragma unroll
    for (int off = 32; off > 0; off >>= 1)
        local += __shfl_down(local, off, 64);
    if (lane == 0) wsum[wave] = local;
    __syncthreads();
    if (threadIdx.x == 0)
        out[0] = (wsum[0] + wsum[1] + wsum[2] + wsum[3]) / (float)F_;
}

extern "C" void kernel_launch(void* const* d_in, const int* in_sizes, int n_in,
                              void* d_out, int out_size, void* d_ws, size_t ws_size,
                              hipStream_t stream)
{
    const float* vertices = (const float*)d_in[0];
    const int*   faces    = (const int*)d_in[1];   // int64 in reference -> int32 on device
    const float* probs    = (const float*)d_in[2];
    float* out = (float*)d_out;

    char* ws = (char*)d_ws;
    float4* C4        = (float4*)ws;
    float4* cellList  = (float4*)(ws + OFF_LIST);
    int*    cellCount = (int*)(ws + OFF_CCNT);
    int*    ndone1    = (int*)(ws + OFF_ND1);
    int*    ndone2    = (int*)(ws + OFF_ND2);
    int*    cnt       = (int*)(ws + OFF_CNT);

    hipMemsetAsync(cellCount, 0, ZERO_BYTES, stream); // cellCount + ndone1 + ndone2
    hipLaunchKernelGGL(build_kernel, dim3(E_ / 256), dim3(256), 0, stream,
                       vertices, faces, C4, cellList, cellCount);
    hipLaunchKernelGGL(count_kernel, dim3(CNT_BLOCKS), dim3(256), 0, stream,
                       C4, cellList, cellCount, cnt, probs, ndone1, ndone2, out);
}

// Round 15
// 88.635 us; speedup vs baseline: 3.2364x; 3.2364x over previous
//
#include <hip/hip_runtime.h>

#define V_ 25000
#define F_ 8192
#define E_ (3 * F_) // 24576

constexpr int CAP  = 101;      // per-edge cap; face clip at 100 makes this lossless
constexpr int GD   = 8;        // grid cells per axis (unit cells over [-4,4), clamped)
constexpr int NC   = GD*GD*GD; // 512 cells
constexpr int CAPC = 6144;     // per-cell list capacity (center cell ~4400 expected)
constexpr int FLATCAP = 384;   // max flat chunks on the pipelined path

// ws layout:
//   C4        float4[E_]        @ 0           (cx,cy,cz, __int_as_float(cell))
//   cellList  float4[NC*CAPC]   @ 393,216     (50,331,648 B)
//   cellCount int[NC]           @ 50,724,864  (2,048 B — the only memset)
//   cnt       int[E_]           @ 50,726,912  (98,304 B — fully overwritten)
constexpr size_t OFF_LIST = 393216;
constexpr size_t OFF_CCNT = 50724864;
constexpr size_t OFF_CNT  = 50726912;

// 26 neighbor patterns in DESCENDING center-ward score (a+b+c); applied as
// offset = pattern * (dirx,diry,dirz). Bijective onto {-1,0,1}^3 \ {0}.
__device__ const int PPAT[26][3] = {
    { 1, 1, 1},
    { 1, 1, 0},{ 1, 0, 1},{ 0, 1, 1},
    { 1, 0, 0},{ 0, 1, 0},{ 0, 0, 1},{ 1, 1,-1},{ 1,-1, 1},{-1, 1, 1},
    { 1,-1, 0},{ 1, 0,-1},{ 0, 1,-1},{-1, 1, 0},{-1, 0, 1},{ 0,-1, 1},
    {-1, 0, 0},{ 0,-1, 0},{ 0, 0,-1},{-1,-1, 1},{-1, 1,-1},{ 1,-1,-1},
    {-1,-1, 0},{-1, 0,-1},{ 0,-1,-1},
    {-1,-1,-1}
};

__device__ __forceinline__ int cell_coord(float c)
{
    return min(GD-1, max(0, (int)floorf(c) + GD/2));
}

// 96 blocks x 256: centroid + cell, LDS-rank counting-append into per-cell lists.
__global__ __launch_bounds__(256) void build_kernel(
    const float* __restrict__ vertices, const int* __restrict__ faces,
    float4* __restrict__ C4, float4* __restrict__ cellList,
    int* __restrict__ cellCount)
{
    __shared__ int lh[NC];
    __shared__ int lbase[NC];
    for (int i = threadIdx.x; i < NC; i += 256) lh[i] = 0;
    __syncthreads();

    const int e = blockIdx.x * 256 + threadIdx.x;
    int f, i0, i1;
    if (e < F_)        { f = e;        i0 = 0; i1 = 1; }
    else if (e < 2*F_) { f = e - F_;   i0 = 1; i1 = 2; }
    else               { f = e - 2*F_; i0 = 2; i1 = 0; }
    int a = faces[f*3 + i0];
    int b = faces[f*3 + i1];
    float cx = 0.5f*(vertices[a*3+0] + vertices[b*3+0]);
    float cy = 0.5f*(vertices[a*3+1] + vertices[b*3+1]);
    float cz = 0.5f*(vertices[a*3+2] + vertices[b*3+2]);
    int cell = (cell_coord(cz)*GD + cell_coord(cy))*GD + cell_coord(cx);
    int rank = atomicAdd(&lh[cell], 1);
    __syncthreads();
    for (int i = threadIdx.x; i < NC; i += 256) {
        int c = lh[i];
        if (c) lbase[i] = atomicAdd(&cellCount[i], c);
    }
    __syncthreads();
    C4[e] = make_float4(cx, cy, cz, __int_as_float(cell));
    cellList[(size_t)cell * CAPC + lbase[cell] + rank] = make_float4(cx, cy, cz, 0.f);
}

// One wave per edge. Own cell first (mass cap-exits here). Survivors build a
// per-wave flat chunk list over the 26 pattern cells (densest-first order)
// and scan it with a depth-4 load pipeline. All loads predicate-guarded.
__global__ __launch_bounds__(256) void count_kernel(
    const float4* __restrict__ C4, const float4* __restrict__ cellList,
    const int* __restrict__ cellCount, int* __restrict__ cnt)
{
    __shared__ unsigned flatLDS[4][FLATCAP + 16];
    const int wave = threadIdx.x >> 6;
    const int lane = threadIdx.x & 63;
    const int e = blockIdx.x * 4 + wave;

    float4 s = C4[e];                          // wave-uniform broadcast
    const float ex = s.x, ey = s.y, ez = s.z;
    const int   cell = __float_as_int(s.w);
    const int ix = cell & 7, iy = (cell >> 3) & 7, iz = cell >> 6;
    const float d2t = (1.0f + 1e-6f) * (1.0f + 1e-6f);

    int count = 0;

    // ---- own cell (1-deep prefetch; ~90% of edges cap-exit here) ----
    {
        const int n = cellCount[cell];         // >=1 (own edge)
        const float4* __restrict__ L = cellList + (size_t)cell * CAPC;
        float4 cur = L[lane];
        for (int base = 0;;) {
            int nb = base + 64;
            bool more = nb < n;
            float4 nxt;
            if (more) nxt = L[nb + lane];
            float dx = ex - cur.x, dy = ey - cur.y, dz = ez - cur.z;
            float d2 = dx*dx + dy*dy + dz*dz;
            bool c = (base + lane < n) && (d2 < d2t);
            count += __popcll(__ballot(c));
            if (count >= CAP) goto done;       // wave-uniform
            if (!more) break;
            cur = nxt; base = nb;
        }
    }

    // ---- survivors: flat chunk list over 26 cells, densest-first ----
    {
        const int dirx = (ix <= 3) ? 1 : -1;
        const int diry = (iy <= 3) ? 1 : -1;
        const int dirz = (iz <= 3) ? 1 : -1;

        int cq = 0, nq = 0, cellq = cell;
        if (lane < 26) {
            int ox = PPAT[lane][0] * dirx;
            int oy = PPAT[lane][1] * diry;
            int oz = PPAT[lane][2] * dirz;
            int x = ix + ox, y = iy + oy, z = iz + oz;
            if (((unsigned)x < (unsigned)GD) & ((unsigned)y < (unsigned)GD) &
                ((unsigned)z < (unsigned)GD)) {
                cellq = cell + oz*64 + oy*8 + ox;
                nq = cellCount[cellq];
                cq = (nq + 63) >> 6;
            }
        }
        int incl = cq;
#pragma unroll
        for (int d = 1; d < 64; d <<= 1) {
            int t = __shfl_up(incl, d, 64);
            if (lane >= d) incl += t;
        }
        const int T = __shfl(incl, 63);        // total chunks (lanes>=26 add 0)
        const int excl = incl - cq;

        if (T == 0) goto done;

        if (T > FLATCAP) {
            // rare exact fallback: simple serial scan, same cells, same order
            for (int q = 0; q < 26; ++q) {
                int ox = PPAT[q][0] * dirx, oy = PPAT[q][1] * diry,
                    oz = PPAT[q][2] * dirz;
                int x = ix + ox, y = iy + oy, z = iz + oz;
                if (((unsigned)x >= (unsigned)GD) | ((unsigned)y >= (unsigned)GD) |
                    ((unsigned)z >= (unsigned)GD)) continue;
                int nc2 = cell + oz*64 + oy*8 + ox;
                int n = cellCount[nc2];
                const float4* __restrict__ L = cellList + (size_t)nc2 * CAPC;
                for (int base = 0; base < n; base += 64) {
                    float4 t4 = L[base + lane];
                    float dx = ex - t4.x, dy = ey - t4.y, dz = ez - t4.z;
                    float d2 = dx*dx + dy*dy + dz*dz;
                    bool c = (base + lane < n) && (d2 < d2t);
                    count += __popcll(__ballot(c));
                    if (count >= CAP) goto done;
                }
            }
            goto done;
        }

        // emit entries: cell(9b)<<14 | chunk(7b)<<7 | nvalid(7b)
        for (int k = 0; k < cq; ++k)
            flatLDS[wave][excl + k] =
                ((unsigned)cellq << 14) | ((unsigned)k << 7)
                | (unsigned)min(64, nq - k*64);
        {
            int pi = T + lane;                 // pads: nvalid=0, own-cell chunk 0
            if (pi < T + 12) flatLDS[wave][pi] = (unsigned)cell << 14;
        }
        asm volatile("s_waitcnt lgkmcnt(0)" ::: "memory"); // same-wave LDS RAW

        const int Tp = (T + 3) & ~3;

#define FADDR(E) (cellList + (size_t)((E) >> 14) * CAPC + (((E) >> 7) & 127) * 64 + lane)
#define PROC(B, EN)                                                        \
        {                                                                  \
            float dx = ex - (B).x, dy = ey - (B).y, dz = ez - (B).z;       \
            float d2 = dx*dx + dy*dy + dz*dz;                              \
            bool c = (lane < (int)((EN) & 127u)) && (d2 < d2t);            \
            count += __popcll(__ballot(c));                                \
            if (count >= CAP) goto done;                                   \
        }

        unsigned e0 = flatLDS[wave][0], e1 = flatLDS[wave][1],
                 e2 = flatLDS[wave][2], e3 = flatLDS[wave][3];
        float4 b0 = *FADDR(e0), b1 = *FADDR(e1), b2 = *FADDR(e2), b3 = *FADDR(e3);
        for (int j = 0;; j += 4) {
            unsigned f0 = flatLDS[wave][j+4], f1 = flatLDS[wave][j+5],
                     f2 = flatLDS[wave][j+6], f3 = flatLDS[wave][j+7];
            float4 n0 = *FADDR(f0), n1 = *FADDR(f1),
                   n2 = *FADDR(f2), n3 = *FADDR(f3);   // issued before compute
            PROC(b0, e0) PROC(b1, e1) PROC(b2, e2) PROC(b3, e3)
            if (j + 4 >= Tp) break;
            e0 = f0; e1 = f1; e2 = f2; e3 = f3;
            b0 = n0; b1 = n1; b2 = n2; b3 = n3;
        }
#undef FADDR
#undef PROC
    }
done:
    if (lane == 0) cnt[e] = count;
}

__global__ __launch_bounds__(1024) void reduce_kernel(
    const int* __restrict__ cnt, const float* __restrict__ probs,
    float* __restrict__ out)
{
    float local = 0.0f;
    for (int f = threadIdx.x; f < F_; f += 1024) {
        // face f's edges in the concatenated [(0,1),(1,2),(2,0)] layout
        float c = (float)(cnt[f] + cnt[F_ + f] + cnt[2*F_ + f]);
        c = fminf(fmaxf(c, 0.0f), 100.0f);
        local += probs[f] * c;
    }
#pragma unroll
    for (int off = 32; off > 0; off >>= 1)
        local += __shfl_down(local, off, 64);
    __shared__ float wsum[16];
    if ((threadIdx.x & 63) == 0) wsum[threadIdx.x >> 6] = local;
    __syncthreads();
    if (threadIdx.x == 0) {
        float t = 0.0f;
#pragma unroll
        for (int w = 0; w < 16; w++) t += wsum[w];
        out[0] = t / (float)F_;
    }
}

extern "C" void kernel_launch(void* const* d_in, const int* in_sizes, int n_in,
                              void* d_out, int out_size, void* d_ws, size_t ws_size,
                              hipStream_t stream)
{
    const float* vertices = (const float*)d_in[0];
    const int*   faces    = (const int*)d_in[1];   // int64 in reference -> int32 on device
    const float* probs    = (const float*)d_in[2];
    float* out = (float*)d_out;

    char* ws = (char*)d_ws;
    float4* C4        = (float4*)ws;
    float4* cellList  = (float4*)(ws + OFF_LIST);
    int*    cellCount = (int*)(ws + OFF_CCNT);
    int*    cnt       = (int*)(ws + OFF_CNT);

    hipMemsetAsync(cellCount, 0, NC * sizeof(int), stream);
    hipLaunchKernelGGL(build_kernel, dim3(E_ / 256), dim3(256), 0, stream,
                       vertices, faces, C4, cellList, cellCount);
    hipLaunchKernelGGL(count_kernel, dim3(E_ / 4), dim3(256), 0, stream,
                       C4, cellList, cellCount, cnt);
    hipLaunchKernelGGL(reduce_kernel, dim3(1), dim3(1024), 0, stream,
                       cnt, probs, out);
}